// Round 8
// baseline (509.863 us; speedup 1.0000x reference)
//
#include <hip/hip_runtime.h>

typedef short short8 __attribute__((ext_vector_type(8)));
typedef float f32x4 __attribute__((ext_vector_type(4)));
typedef int   i32x4 __attribute__((ext_vector_type(4)));
typedef unsigned short u16;
typedef unsigned int u32;

__device__ __forceinline__ float b2f(u16 u){ union{u32 i; float f;} v; v.i=((u32)u)<<16; return v.f; }
__device__ __forceinline__ u16 f2b(float f){ union{float f; u32 i;} v; v.f=f; return (u16)((v.i + 0x7fffu + ((v.i>>16)&1u))>>16); }
__device__ __forceinline__ float loadv(const void* p, long i, bool isbf){
  return isbf ? b2f(((const u16*)p)[i]) : ((const float*)p)[i];
}

// ---------------- dtype detector: bf16 buffers vs fp32 buffers ----------------
__global__ void detect_bf16(const void* x, int n, int* flag){
  __shared__ int cnt;
  if (threadIdx.x==0) cnt = 0;
  __syncthreads();
  int m = n < 4096 ? n : 4096;
  int good = 0;
  for (int i = threadIdx.x; i < m; i += 256){
    u16 u = ((const u16*)x)[i];
    int e = (u >> 7) & 0xff;
    if (u == 0 || (e >= 100 && e <= 140)) good++;
  }
  atomicAdd(&cnt, good);
  __syncthreads();
  if (threadIdx.x==0){
    flag[0] = (cnt >= (m*3)/4) ? 1 : 0;
    flag[1] = 1;  // constant "is bf16" for internal buffers
  }
}

// ---------------- fused init: W1/W2 transpose+convert + zero counts ----------------
__global__ __launch_bounds__(256) void init_k(const void* __restrict__ W1, const void* __restrict__ W2,
                                              u16* __restrict__ WT1, u16* __restrict__ WT2,
                                              int* __restrict__ counts, int N, const int* __restrict__ flag){
  const bool wbf = *flag != 0;
  int gid = blockIdx.x*256 + threadIdx.x;
  if (gid < 128*128){
    int i = gid, k = i >> 7, c = i & 127;
    WT1[c*128 + k] = wbf ? ((const u16*)W1)[i] : f2b(((const float*)W1)[i]);
  } else if (gid < 128*128 + 128*160){
    int i = gid - 128*128, k = i / 160, c = i - k*160;
    WT2[c*128 + k] = wbf ? ((const u16*)W2)[i] : f2b(((const float*)W2)[i]);
  } else {
    int i = gid - (128*128 + 128*160);
    if (i < N) counts[i] = 0;
  }
}

// ---------------- CSR build, XCD-partitioned ----------------
__global__ __launch_bounds__(256) void count_x(const int* __restrict__ dst,
    int* __restrict__ counts, int E, int N, int nchunk){
  int r = blockIdx.x & 7;
  int chunk = blockIdx.x >> 3;
  int lo = (int)(((long)N * r) >> 3);
  int hi = (int)(((long)N * (r+1)) >> 3);
  int per = (E + nchunk - 1) / nchunk;
  int s = chunk * per, t = min(E, s + per);
  for (int e = s + threadIdx.x; e < t; e += 256){
    int d = dst[e];
    if (d >= lo && d < hi) atomicAdd(&counts[d], 1);
  }
}

__global__ __launch_bounds__(256) void scan_bsum(const int* __restrict__ counts, int* __restrict__ bsum, int N){
  __shared__ int sm[256];
  int t = threadIdx.x, i = blockIdx.x*256 + t;
  sm[t] = (i < N) ? counts[i] : 0;
  __syncthreads();
  for (int off = 128; off; off >>= 1){
    if (t < off) sm[t] += sm[t+off];
    __syncthreads();
  }
  if (t == 0) bsum[blockIdx.x] = sm[0];
}

__global__ __launch_bounds__(1024) void scan_top(const int* __restrict__ bsum, int* __restrict__ bscan, int B){
  __shared__ int sm[1024];
  int t = threadIdx.x;
  int v = (t < B) ? bsum[t] : 0;
  sm[t] = v;
  __syncthreads();
  for (int off = 1; off < 1024; off <<= 1){
    int x = (t >= off) ? sm[t-off] : 0;
    __syncthreads();
    sm[t] += x;
    __syncthreads();
  }
  if (t < B) bscan[t] = sm[t] - v;   // exclusive
}

// scan_final also zeroes counts (value already consumed) -> removes 2nd memset
__global__ __launch_bounds__(256) void scan_final(const int* __restrict__ counts_in, int* __restrict__ counts_clr,
                                                  const int* __restrict__ bscan,
                                                  int* __restrict__ rp, int N, int E){
  __shared__ int sm[256];
  int t = threadIdx.x, i = blockIdx.x*256 + t;
  int v = (i < N) ? counts_in[i] : 0;
  sm[t] = v;
  __syncthreads();
  for (int off = 1; off < 256; off <<= 1){
    int x = (t >= off) ? sm[t-off] : 0;
    __syncthreads();
    sm[t] += x;
    __syncthreads();
  }
  if (i < N){ rp[i] = bscan[blockIdx.x] + sm[t] - v; counts_clr[i] = 0; }
  if (i == 0) rp[N] = E;
}

// ---------------- fused scatter_x || gemm1(+al epilogue) ----------------
// Roles interleaved at granularity 8: even (blockIdx>>3) groups below 2*8*nchunk
// are scatter blocks (r = blockIdx&7 preserves the XCD->region mapping; chunk =
// blockIdx>>4), odd groups + trailing blocks are gemm tiles. Each CU hosts a mix
// of fabric-bound scatter waves and MFMA-bound gemm waves -> the independent CSR
// scatter hides under gemm1. Scatter role ignores the (static) LDS allocation.
__global__ __launch_bounds__(256) void scat_gemm1(
    const int* __restrict__ esrc, const int* __restrict__ edst,
    const int* __restrict__ rp, int* __restrict__ cur, int* __restrict__ psrc,
    int E, int nchunk,
    const void* __restrict__ X, const u16* __restrict__ WT,
    const void* __restrict__ as_, const void* __restrict__ ad_,
    u16* __restrict__ OUT, float* __restrict__ als, float* __restrict__ ald,
    int N, const int* __restrict__ flagX, const int* __restrict__ flagW){
  __shared__ u16 wt[128][136];
  __shared__ float s_as[128], s_ad[128];
  int b = blockIdx.x;
  int two = 2*8*nchunk;
  if (b < two && (((b >> 3) & 1) == 0)){
    // ---- scatter role ----
    int r = b & 7;
    int chunk = b >> 4;
    int lo = (int)(((long)N * r) >> 3);
    int hi = (int)(((long)N * (r+1)) >> 3);
    int per = (E + nchunk - 1) / nchunk;
    int s = chunk * per, t = min(E, s + per);
    for (int e = s + threadIdx.x; e < t; e += 256){
      int d = edst[e];
      if (d >= lo && d < hi){
        int pos = rp[d] + atomicAdd(&cur[d], 1);
        psrc[pos] = esrc[e];
      }
    }
    return;
  }
  // ---- gemm role (M=128, C=32) ----
  int bid = (b < two) ? ((b >> 4)*8 + (b & 7)) : (8*nchunk + (b - two));
  int NT1 = (N + 63) >> 6;
  if (bid >= NT1) return;
  const bool xbf = *flagX != 0;
  const bool abf = *flagW != 0;
  int tid = threadIdx.x;
  for (int i = tid; i < 128*16; i += 256){
    int c = i >> 4, k8 = (i & 15) << 3;
    *(short8*)&wt[c][k8] = *(const short8*)&WT[c*128 + k8];
  }
  for (int i = tid; i < 128; i += 256){
    s_as[i] = loadv(as_, i, abf);
    s_ad[i] = loadv(ad_, i, abf);
  }
  __syncthreads();
  int wave = tid >> 6, lane = tid & 63;
  int quad = lane >> 4, l16 = lane & 15;
  int rowbase = bid*64 + wave*16;
  int rr = rowbase + l16; if (rr >= N) rr = N-1;
  f32x4 acc[8];
  #pragma unroll
  for (int t=0;t<8;t++) acc[t] = (f32x4){0.f,0.f,0.f,0.f};
  #pragma unroll
  for (int kt = 0; kt < 4; kt++){
    int kb = kt*32 + quad*8;
    short8 a;
    if (xbf){
      a = *(const short8*)((const u16*)X + (size_t)rr*128 + kb);
    } else {
      const float* xf = (const float*)X + (size_t)rr*128 + kb;
      #pragma unroll
      for (int j=0;j<8;j++) a[j] = (short)f2b(xf[j]);
    }
    #pragma unroll
    for (int t=0;t<8;t++){
      short8 bb = *(const short8*)&wt[t*16 + l16][kb];
      acc[t] = __builtin_amdgcn_mfma_f32_16x16x32_bf16(a, bb, acc[t], 0, 0, 0);
    }
  }
  #pragma unroll
  for (int t=0;t<8;t++){
    #pragma unroll
    for (int r=0;r<4;r++){
      int row = rowbase + quad*4 + r;
      if (row < N) OUT[(size_t)row*128 + t*16 + l16] = f2b(acc[t][r]);
    }
  }
  // fused al epilogue (C=32: head = t>>1, static per tile)
  float ps[4][4], pd[4][4];
  #pragma unroll
  for (int r=0;r<4;r++)
    #pragma unroll
    for (int h=0;h<4;h++){ ps[r][h]=0.f; pd[r][h]=0.f; }
  #pragma unroll
  for (int t=0;t<8;t++){
    const int hh = t >> 1;
    int col = t*16 + l16;
    float avs = s_as[col], avd = s_ad[col];
    #pragma unroll
    for (int r=0;r<4;r++){ ps[r][hh] += acc[t][r]*avs; pd[r][hh] += acc[t][r]*avd; }
  }
  #pragma unroll
  for (int off=1; off<16; off<<=1){
    #pragma unroll
    for (int r=0;r<4;r++)
      #pragma unroll
      for (int h=0;h<4;h++){
        ps[r][h] += __shfl_xor(ps[r][h], off);
        pd[r][h] += __shfl_xor(pd[r][h], off);
      }
  }
  float vs = 0.f, vd = 0.f;
  #pragma unroll
  for (int r=0;r<4;r++)
    #pragma unroll
    for (int h=0;h<4;h++)
      if (l16 == r*4 + h){ vs = ps[r][h]; vd = pd[r][h]; }
  int wrow = rowbase + quad*4 + (l16 >> 2);
  if (wrow < N){
    als[wrow*4 + (l16 & 3)] = vs;
    ald[wrow*4 + (l16 & 3)] = vd;
  }
}

// ---------------- GEMM + fused attention pre-logits (layer 2) ----------------
template<int M, int C>
__global__ __launch_bounds__(256) void gemm_al(const void* __restrict__ X, const u16* __restrict__ WT,
                                               const void* __restrict__ as_, const void* __restrict__ ad_,
                                               u16* __restrict__ OUT, u16* __restrict__ OUT2,
                                               float* __restrict__ als, float* __restrict__ ald,
                                               int N, const int* __restrict__ flagX, const int* __restrict__ flagW){
  __shared__ u16 wt[M][136];            // +8 pad: 2-way bank alias only (free)
  __shared__ float s_as[4*C], s_ad[4*C];
  const bool xbf = *flagX != 0;
  const bool abf = *flagW != 0;
  int tid = threadIdx.x;
  for (int i = tid; i < M*16; i += 256){
    int c = i >> 4, k8 = (i & 15) << 3;
    *(short8*)&wt[c][k8] = *(const short8*)&WT[c*128 + k8];
  }
  for (int i = tid; i < 4*C; i += 256){
    s_as[i] = loadv(as_, i, abf);
    s_ad[i] = loadv(ad_, i, abf);
  }
  __syncthreads();
  int wave = tid >> 6, lane = tid & 63;
  int quad = lane >> 4, l16 = lane & 15;
  int rowbase = blockIdx.x*64 + wave*16;
  int rr = rowbase + l16; if (rr >= N) rr = N-1;
  const int NT = M/16;
  f32x4 acc[NT];
  #pragma unroll
  for (int t=0;t<NT;t++) acc[t] = (f32x4){0.f,0.f,0.f,0.f};
  #pragma unroll
  for (int kt = 0; kt < 4; kt++){
    int kb = kt*32 + quad*8;
    short8 a;
    if (xbf){
      a = *(const short8*)((const u16*)X + (size_t)rr*128 + kb);
    } else {
      const float* xf = (const float*)X + (size_t)rr*128 + kb;
      #pragma unroll
      for (int j=0;j<8;j++) a[j] = (short)f2b(xf[j]);
    }
    #pragma unroll
    for (int t=0;t<NT;t++){
      short8 b = *(const short8*)&wt[t*16 + l16][kb];
      acc[t] = __builtin_amdgcn_mfma_f32_16x16x32_bf16(a, b, acc[t], 0, 0, 0);
    }
  }
  // ---- store OUT (bf16) ----
  #pragma unroll
  for (int t=0;t<NT;t++){
    #pragma unroll
    for (int r=0;r<4;r++){
      int row = rowbase + quad*4 + r;
      if (row < N){
        u16 val = f2b(acc[t][r]);
        if (M > 128 && t*16 >= 128) OUT2[(size_t)row*32 + (t*16 - 128) + l16] = val;
        else                        OUT [(size_t)row*128 + t*16 + l16]        = val;
      }
    }
  }
  // ---- fused al epilogue (fp32 acc, static head indexing) ----
  float ps[4][4], pd[4][4];   // [r][h]
  #pragma unroll
  for (int r=0;r<4;r++)
    #pragma unroll
    for (int h=0;h<4;h++){ ps[r][h]=0.f; pd[r][h]=0.f; }
  #pragma unroll
  for (int t=0;t<NT;t++){
    const int hlo = (t*16)/C;
    const int hhi = (t*16+15)/C;
    int col = t*16 + l16;
    float avs = s_as[col], avd = s_ad[col];
    if (hlo == hhi){
      #pragma unroll
      for (int r=0;r<4;r++){ ps[r][hlo] += acc[t][r]*avs; pd[r][hlo] += acc[t][r]*avd; }
    } else {
      if (l16 < hhi*C - t*16){
        #pragma unroll
        for (int r=0;r<4;r++){ ps[r][hlo] += acc[t][r]*avs; pd[r][hlo] += acc[t][r]*avd; }
      } else {
        #pragma unroll
        for (int r=0;r<4;r++){ ps[r][hhi] += acc[t][r]*avs; pd[r][hhi] += acc[t][r]*avd; }
      }
    }
  }
  #pragma unroll
  for (int off=1; off<16; off<<=1){
    #pragma unroll
    for (int r=0;r<4;r++)
      #pragma unroll
      for (int h=0;h<4;h++){
        ps[r][h] += __shfl_xor(ps[r][h], off);
        pd[r][h] += __shfl_xor(pd[r][h], off);
      }
  }
  float vs = 0.f, vd = 0.f;
  #pragma unroll
  for (int r=0;r<4;r++)
    #pragma unroll
    for (int h=0;h<4;h++)
      if (l16 == r*4 + h){ vs = ps[r][h]; vd = pd[r][h]; }
  int wrow = rowbase + quad*4 + (l16 >> 2);
  if (wrow < N){
    als[wrow*4 + (l16 & 3)] = vs;
    ald[wrow*4 + (l16 & 3)] = vd;
  }
}

// ---------------- layer-1 aggregation: wave per node (round-2 structure) ----------------
__global__ __launch_bounds__(256) void agg1(const u16* __restrict__ h1,
    const float* __restrict__ als, const float* __restrict__ ald, const void* __restrict__ b1,
    const int* __restrict__ rp, const int* __restrict__ psrc,
    u16* __restrict__ hrelu, int N, const int* __restrict__ flag){
  __shared__ __align__(16) int   sbuf[4][16];
  __shared__ __align__(16) float ebT[4][4*20];   // stride 20 dwords = 80 B (16-aligned)
  const bool isbf = *flag != 0;
  int wave = threadIdx.x >> 6, lane = threadIdx.x & 63;
  int node = blockIdx.x*4 + wave;
  bool live = node < N;
  int nd = live ? node : 0;
  int hd = lane >> 4;                 // head of output channels 2*lane
  int eidx = lane >> 2, hA = lane & 3;
  int beg = __builtin_amdgcn_readfirstlane(rp[nd]);
  int end = __builtin_amdgcn_readfirstlane(rp[nd+1]);
  if (!live){ beg = 0; end = 0; }
  float advA = ald[nd*4 + hA];
  const char* hb = (const char*)h1;
  int lane4 = lane << 2;
  int* sb = sbuf[wave];
  float* eb = ebT[wave];
  float a0 = 0.f, a1 = 0.f;
  float sp = 0.f;
  for (int cbeg = beg; cbeg < end; cbeg += 16){
    int cnt = min(16, end - cbeg);
    int e = cbeg + eidx;
    bool vv = e < end;
    int ec = vv ? e : beg;
    int s = psrc[ec];
    float lv = als[s*4 + hA] + advA;
    lv = fmaxf(lv, 0.2f*lv);
    float ex = vv ? __expf(lv) : 0.f;
    sp += ex;
    eb[hA*20 + eidx] = ex;
    if (hA == 0) sb[eidx] = vv ? (s << 8) : 0;   // row byte offset (256 B rows)
    for (int j0 = 0; j0 < cnt; j0 += 4){
      i32x4 off4 = *(const i32x4*)&sb[j0];                 // uniform b128 broadcast
      f32x4 ex4  = *(const f32x4*)&eb[hd*20 + j0];         // per-head-group b128
      u32 p[4];
      #pragma unroll
      for (int i=0;i<4;i++) p[i] = *(const u32*)(hb + (u32)(off4[i] + lane4));
      #pragma unroll
      for (int i=0;i<4;i++){
        union{u32 u; float f;} w;
        w.u = p[i] << 16;         a0 += ex4[i]*w.f;
        w.u = p[i] & 0xffff0000u; a1 += ex4[i]*w.f;
      }
    }
  }
  sp += __shfl_xor(sp, 4);  sp += __shfl_xor(sp, 8);
  sp += __shfl_xor(sp, 16); sp += __shfl_xor(sp, 32);
  float sum = __shfl(sp, hd);          // lane h holds head-h sum
  if (live){
    float inv = 1.f/(sum + 1e-16f);
    float v0 = a0*inv + loadv(b1, 2*lane,     isbf);
    float v1 = a1*inv + loadv(b1, 2*lane + 1, isbf);
    v0 = v0 > 0.f ? v0 : 0.f;
    v1 = v1 > 0.f ? v1 : 0.f;
    u32 packed = (u32)f2b(v0) | ((u32)f2b(v1) << 16);
    *(u32*)(hrelu + (size_t)node*128 + 2*lane) = packed;
  }
}

// ---------------- layer-2 aggregation + head-mean + bias + log_softmax ----------------
__global__ __launch_bounds__(256) void agg2(const u16* __restrict__ h2m, const u16* __restrict__ h2t,
    const float* __restrict__ als, const float* __restrict__ ald, const void* __restrict__ b2,
    const int* __restrict__ rp, const int* __restrict__ psrc,
    void* __restrict__ out, int N, const int* __restrict__ flag){
  __shared__ __align__(16) int   sbuf[4][16];
  __shared__ __align__(16) float ebT[4][4*20];
  __shared__ __align__(16) float sm[4][160];
  const bool isbf = *flag != 0;
  int wave = threadIdx.x >> 6, lane = threadIdx.x & 63;
  int node = blockIdx.x*4 + wave;
  bool live = node < N;
  int nd = live ? node : 0;
  int g = lane >> 4, s = lane & 15;
  int hm = s / 5;                       // head of main channels 8s..8s+7
  int moff = s << 4;                    // main byte offset within 256B row
  int tof  = s << 2;                    // tail byte offset within 64B row
  int eidx = lane >> 2, hA = lane & 3;
  int beg = __builtin_amdgcn_readfirstlane(rp[nd]);
  int end = __builtin_amdgcn_readfirstlane(rp[nd+1]);
  if (!live){ beg = 0; end = 0; }
  float advA = ald[nd*4 + hA];
  const char* hbm = (const char*)h2m;
  const char* hbt = (const char*)h2t;
  int* sb = sbuf[wave];
  float* eb = ebT[wave];
  float am[8] = {0.f,0.f,0.f,0.f,0.f,0.f,0.f,0.f};
  float at0 = 0.f, at1 = 0.f;
  float sp = 0.f;
  for (int cbeg = beg; cbeg < end; cbeg += 16){
    int cnt = min(16, end - cbeg);
    int e = cbeg + eidx;
    bool vv = e < end;
    int ec = vv ? e : beg;
    int src = psrc[ec];
    float lv = als[src*4 + hA] + advA;
    lv = fmaxf(lv, 0.2f*lv);
    float ex = vv ? __expf(lv) : 0.f;
    sp += ex;
    eb[hA*20 + eidx] = ex;
    if (hA == 0) sb[eidx] = vv ? src : 0;       // raw src index
    for (int j0 = 0; j0 < cnt; j0 += 4){
      int sv    = sb[j0 + g];                    // 4 srcs, 16-lane broadcast
      float exm = eb[hm*20 + j0 + g];
      float ext = eb[3*20  + j0 + g];
      i32x4 P = *(const i32x4*)(hbm + ((((u32)sv) << 8) + moff));
      u32   q = *(const u32*) (hbt + ((((u32)sv) << 6) + tof));
      union{u32 u; float f;} w;
      #pragma unroll
      for (int i=0;i<4;i++){
        u32 pv = (u32)P[i];
        w.u = pv << 16;         am[2*i]   += exm*w.f;
        w.u = pv & 0xffff0000u; am[2*i+1] += exm*w.f;
      }
      w.u = q << 16;         at0 += ext*w.f;
      w.u = q & 0xffff0000u; at1 += ext*w.f;
    }
  }
  // softmax denominators: lane l ends with sum of head (l&3)
  sp += __shfl_xor(sp, 4);  sp += __shfl_xor(sp, 8);
  sp += __shfl_xor(sp, 16); sp += __shfl_xor(sp, 32);
  float Sm = __shfl(sp, hm);
  float S3 = __shfl(sp, 3);
  // cross-group accumulator reduce (edges were partitioned across the 4 groups)
  #pragma unroll
  for (int k=0;k<8;k++){ am[k] += __shfl_xor(am[k],16); am[k] += __shfl_xor(am[k],32); }
  at0 += __shfl_xor(at0,16); at0 += __shfl_xor(at0,32);
  at1 += __shfl_xor(at1,16); at1 += __shfl_xor(at1,32);
  if (lane < 16){
    float invm = 1.f/(Sm + 1e-16f);
    float invt = 1.f/(S3 + 1e-16f);
    f32x4 v0 = {am[0]*invm, am[1]*invm, am[2]*invm, am[3]*invm};
    f32x4 v1 = {am[4]*invm, am[5]*invm, am[6]*invm, am[7]*invm};
    *(f32x4*)&sm[wave][8*s]     = v0;
    *(f32x4*)&sm[wave][8*s + 4] = v1;
    sm[wave][128 + 2*s] = at0*invt;
    sm[wave][129 + 2*s] = at1*invt;
  }
  __syncthreads();
  float v = -__builtin_inff();
  if (lane < 40)
    v = (sm[wave][lane] + sm[wave][40+lane] + sm[wave][80+lane] + sm[wave][120+lane]) * 0.25f
        + loadv(b2, lane, isbf);
  float mxo = v;
  for (int o = 32; o; o >>= 1) mxo = fmaxf(mxo, __shfl_xor(mxo, o));
  float exl = (lane < 40) ? __expf(v - mxo) : 0.f;
  float S = exl;
  for (int o = 32; o; o >>= 1) S += __shfl_xor(S, o);
  if (live && lane < 40){
    float r = v - mxo - __logf(S);
    if (isbf) ((u16*)out)[(size_t)node*40 + lane] = f2b(r);
    else      ((float*)out)[(size_t)node*40 + lane] = r;
  }
}

extern "C" void kernel_launch(void* const* d_in, const int* in_sizes, int n_in,
                              void* d_out, int out_size, void* d_ws, size_t ws_size,
                              hipStream_t stream){
  const void* x   = d_in[0];
  const int*  ei  = (const int*)d_in[1];
  const void* W1  = d_in[2];
  const void* as1 = d_in[3];
  const void* ad1 = d_in[4];
  const void* b1  = d_in[5];
  const void* W2  = d_in[6];
  const void* as2 = d_in[7];
  const void* ad2 = d_in[8];
  const void* b2  = d_in[9];

  const int N = in_sizes[0] / 128;
  const int E = in_sizes[1] / 2;
  const int* esrc = ei;
  const int* edst = ei + E;

  char* w = (char*)d_ws;
  size_t off = 0;
  auto take = [&](size_t bytes)->void*{
    void* p = w + off;
    off = (off + bytes + 255) & ~(size_t)255;
    return p;
  };
  u16*   h12    = (u16*)take((size_t)N*128*2);   // h1 [N,128] then h2m [N,128] (aliased)
  u16*   h2t    = (u16*)take((size_t)N*32*2);    // h2 tail channels 128..159
  u16*   hrelu  = (u16*)take((size_t)N*128*2);
  float* als1   = (float*)take((size_t)N*4*4);
  float* ald1   = (float*)take((size_t)N*4*4);
  float* als2   = (float*)take((size_t)N*4*4);
  float* ald2   = (float*)take((size_t)N*4*4);
  int*   rowptr = (int*)take((size_t)(N+1)*4);
  int*   counts = (int*)take((size_t)N*4);
  int*   bsum   = (int*)take(1024*4);
  int*   bscan  = (int*)take(1024*4);
  int*   psrc   = (int*)take((size_t)E*4);
  int*   flag   = (int*)take(64);
  u16*   wt1    = (u16*)take(128*128*2);
  u16*   wt2    = (u16*)take(160*128*2);

  const int B = (N + 255) / 256;
  const int NCHUNK = 128;               // blocks per region-group; scatter grid = 8*NCHUNK
  const int INIT_W = 128*128 + 128*160;

  detect_bf16<<<1, 256, 0, stream>>>(x, N*128, flag);
  init_k<<<(INIT_W + N + 255)/256, 256, 0, stream>>>(W1, W2, wt1, wt2, counts, N, flag);

  // CSR count + scan; scan_final re-zeroes counts for the scatter pass
  count_x<<<8*NCHUNK, 256, 0, stream>>>(edst, counts, E, N, NCHUNK);
  scan_bsum<<<B, 256, 0, stream>>>(counts, bsum, N);
  scan_top<<<1, 1024, 0, stream>>>(bsum, bscan, B);
  scan_final<<<B, 256, 0, stream>>>(counts, counts, bscan, rowptr, N, E);

  // fused: scatter (1024 role-blocks, XCD-mapped) || gemm1+al (1563 tiles)
  const int NT1 = (N + 63) / 64;
  const int SGGRID = 2*8*NCHUNK + (NT1 > 8*NCHUNK ? NT1 - 8*NCHUNK : 0);
  scat_gemm1<<<SGGRID, 256, 0, stream>>>(esrc, edst, rowptr, counts, psrc, E, NCHUNK,
                                         x, wt1, as1, ad1, h12, als1, ald1, N, flag, flag);

  agg1<<<(N+3)/4, 256, 0, stream>>>(h12, als1, ald1, b1, rowptr, psrc, hrelu, N, flag);

  // layer 2 (h2m overwrites h1 region; hrelu input is internal bf16 -> flag+1)
  gemm_al<160,40><<<(N+63)/64, 256, 0, stream>>>(hrelu, wt2, as2, ad2, h12, h2t,
                                                 als2, ald2, N, flag+1, flag);
  agg2<<<(N+3)/4, 256, 0, stream>>>(h12, h2t, als2, ald2, b2, rowptr, psrc, d_out, N, flag);
}

// Round 9
// 476.369 us; speedup vs baseline: 1.0703x; 1.0703x over previous
//
#include <hip/hip_runtime.h>

typedef short short8 __attribute__((ext_vector_type(8)));
typedef float f32x4 __attribute__((ext_vector_type(4)));
typedef int   i32x4 __attribute__((ext_vector_type(4)));
typedef unsigned short u16;
typedef unsigned int u32;

__device__ __forceinline__ float b2f(u16 u){ union{u32 i; float f;} v; v.i=((u32)u)<<16; return v.f; }
__device__ __forceinline__ u16 f2b(float f){ union{float f; u32 i;} v; v.f=f; return (u16)((v.i + 0x7fffu + ((v.i>>16)&1u))>>16); }
__device__ __forceinline__ float loadv(const void* p, long i, bool isbf){
  return isbf ? b2f(((const u16*)p)[i]) : ((const float*)p)[i];
}

// ---------------- dtype detector: bf16 buffers vs fp32 buffers ----------------
__global__ void detect_bf16(const void* x, int n, int* flag){
  __shared__ int cnt;
  if (threadIdx.x==0) cnt = 0;
  __syncthreads();
  int m = n < 4096 ? n : 4096;
  int good = 0;
  for (int i = threadIdx.x; i < m; i += 256){
    u16 u = ((const u16*)x)[i];
    int e = (u >> 7) & 0xff;
    if (u == 0 || (e >= 100 && e <= 140)) good++;
  }
  atomicAdd(&cnt, good);
  __syncthreads();
  if (threadIdx.x==0){
    flag[0] = (cnt >= (m*3)/4) ? 1 : 0;
    flag[1] = 1;  // constant "is bf16" for internal buffers
  }
}

// ---------------- fused init: W1/W2 transpose+convert + zero counts ----------------
__global__ __launch_bounds__(256) void init_k(const void* __restrict__ W1, const void* __restrict__ W2,
                                              u16* __restrict__ WT1, u16* __restrict__ WT2,
                                              int* __restrict__ counts, int N, const int* __restrict__ flag){
  const bool wbf = *flag != 0;
  int gid = blockIdx.x*256 + threadIdx.x;
  if (gid < 128*128){
    int i = gid, k = i >> 7, c = i & 127;
    WT1[c*128 + k] = wbf ? ((const u16*)W1)[i] : f2b(((const float*)W1)[i]);
  } else if (gid < 128*128 + 128*160){
    int i = gid - 128*128, k = i / 160, c = i - k*160;
    WT2[c*128 + k] = wbf ? ((const u16*)W2)[i] : f2b(((const float*)W2)[i]);
  } else {
    int i = gid - (128*128 + 128*160);
    if (i < N) counts[i] = 0;
  }
}

// ---------------- CSR count: single-pass (edge list read once; atomics are small
// L2-side RMW messages, no write-allocate amplification - round-5 evidence) ----
__global__ __launch_bounds__(256) void count_1p(const int* __restrict__ dst, int* __restrict__ counts, int E){
  int i = blockIdx.x*256 + threadIdx.x;
  int stride = gridDim.x*256;
  for (int e = i; e < E; e += stride) atomicAdd(&counts[dst[e]], 1);
}

// ---------------- CSR scatter: XCD-partitioned (psrc lines fill completely in the
// owning XCD's L2 before write-back; single-pass variant had 16x amplification) ----
__global__ __launch_bounds__(256) void scatter_x(const int* __restrict__ src, const int* __restrict__ dst,
    const int* __restrict__ rp, int* __restrict__ cur,
    int* __restrict__ psrc, int E, int N, int nchunk){
  int r = blockIdx.x & 7;
  int chunk = blockIdx.x >> 3;
  int lo = (int)(((long)N * r) >> 3);
  int hi = (int)(((long)N * (r+1)) >> 3);
  int per = (E + nchunk - 1) / nchunk;
  int s = chunk * per, t = min(E, s + per);
  for (int e = s + threadIdx.x; e < t; e += 256){
    int d = dst[e];
    if (d >= lo && d < hi){
      int pos = rp[d] + atomicAdd(&cur[d], 1);
      psrc[pos] = src[e];
    }
  }
}

__global__ __launch_bounds__(256) void scan_bsum(const int* __restrict__ counts, int* __restrict__ bsum, int N){
  __shared__ int sm[256];
  int t = threadIdx.x, i = blockIdx.x*256 + t;
  sm[t] = (i < N) ? counts[i] : 0;
  __syncthreads();
  for (int off = 128; off; off >>= 1){
    if (t < off) sm[t] += sm[t+off];
    __syncthreads();
  }
  if (t == 0) bsum[blockIdx.x] = sm[0];
}

__global__ __launch_bounds__(1024) void scan_top(const int* __restrict__ bsum, int* __restrict__ bscan, int B){
  __shared__ int sm[1024];
  int t = threadIdx.x;
  int v = (t < B) ? bsum[t] : 0;
  sm[t] = v;
  __syncthreads();
  for (int off = 1; off < 1024; off <<= 1){
    int x = (t >= off) ? sm[t-off] : 0;
    __syncthreads();
    sm[t] += x;
    __syncthreads();
  }
  if (t < B) bscan[t] = sm[t] - v;   // exclusive
}

// scan_final also zeroes counts (value already consumed) -> no 2nd memset
__global__ __launch_bounds__(256) void scan_final(const int* __restrict__ counts_in, int* __restrict__ counts_clr,
                                                  const int* __restrict__ bscan,
                                                  int* __restrict__ rp, int N, int E){
  __shared__ int sm[256];
  int t = threadIdx.x, i = blockIdx.x*256 + t;
  int v = (i < N) ? counts_in[i] : 0;
  sm[t] = v;
  __syncthreads();
  for (int off = 1; off < 256; off <<= 1){
    int x = (t >= off) ? sm[t-off] : 0;
    __syncthreads();
    sm[t] += x;
    __syncthreads();
  }
  if (i < N){ rp[i] = bscan[blockIdx.x] + sm[t] - v; counts_clr[i] = 0; }
  if (i == 0) rp[N] = E;
}

// ---------------- GEMM + fused attention pre-logits ----------------
// OUT[N,M] = X[N,128] * W[128,M] (bf16 out, fp32 acc). Cols 0..127 -> OUT,
// cols 128.. -> OUT2 (split keeps agg gather line-aligned). Epilogue computes
// als/ald from the fp32 accumulators in-register (static head indexing).
template<int M, int C>
__global__ __launch_bounds__(256) void gemm_al(const void* __restrict__ X, const u16* __restrict__ WT,
                                               const void* __restrict__ as_, const void* __restrict__ ad_,
                                               u16* __restrict__ OUT, u16* __restrict__ OUT2,
                                               float* __restrict__ als, float* __restrict__ ald,
                                               int N, const int* __restrict__ flagX, const int* __restrict__ flagW){
  __shared__ u16 wt[M][136];            // +8 pad: 2-way bank alias only (free)
  __shared__ float s_as[4*C], s_ad[4*C];
  const bool xbf = *flagX != 0;
  const bool abf = *flagW != 0;
  int tid = threadIdx.x;
  for (int i = tid; i < M*16; i += 256){
    int c = i >> 4, k8 = (i & 15) << 3;
    *(short8*)&wt[c][k8] = *(const short8*)&WT[c*128 + k8];
  }
  for (int i = tid; i < 4*C; i += 256){
    s_as[i] = loadv(as_, i, abf);
    s_ad[i] = loadv(ad_, i, abf);
  }
  __syncthreads();
  int wave = tid >> 6, lane = tid & 63;
  int quad = lane >> 4, l16 = lane & 15;
  int rowbase = blockIdx.x*64 + wave*16;
  int rr = rowbase + l16; if (rr >= N) rr = N-1;
  const int NT = M/16;
  f32x4 acc[NT];
  #pragma unroll
  for (int t=0;t<NT;t++) acc[t] = (f32x4){0.f,0.f,0.f,0.f};
  #pragma unroll
  for (int kt = 0; kt < 4; kt++){
    int kb = kt*32 + quad*8;
    short8 a;
    if (xbf){
      a = *(const short8*)((const u16*)X + (size_t)rr*128 + kb);
    } else {
      const float* xf = (const float*)X + (size_t)rr*128 + kb;
      #pragma unroll
      for (int j=0;j<8;j++) a[j] = (short)f2b(xf[j]);
    }
    #pragma unroll
    for (int t=0;t<NT;t++){
      short8 b = *(const short8*)&wt[t*16 + l16][kb];
      acc[t] = __builtin_amdgcn_mfma_f32_16x16x32_bf16(a, b, acc[t], 0, 0, 0);
    }
  }
  // ---- store OUT (bf16) ----
  #pragma unroll
  for (int t=0;t<NT;t++){
    #pragma unroll
    for (int r=0;r<4;r++){
      int row = rowbase + quad*4 + r;
      if (row < N){
        u16 val = f2b(acc[t][r]);
        if (M > 128 && t*16 >= 128) OUT2[(size_t)row*32 + (t*16 - 128) + l16] = val;
        else                        OUT [(size_t)row*128 + t*16 + l16]        = val;
      }
    }
  }
  // ---- fused al epilogue (fp32 acc, static head indexing) ----
  float ps[4][4], pd[4][4];   // [r][h]
  #pragma unroll
  for (int r=0;r<4;r++)
    #pragma unroll
    for (int h=0;h<4;h++){ ps[r][h]=0.f; pd[r][h]=0.f; }
  #pragma unroll
  for (int t=0;t<NT;t++){
    const int hlo = (t*16)/C;
    const int hhi = (t*16+15)/C;
    int col = t*16 + l16;
    float avs = s_as[col], avd = s_ad[col];
    if (hlo == hhi){
      #pragma unroll
      for (int r=0;r<4;r++){ ps[r][hlo] += acc[t][r]*avs; pd[r][hlo] += acc[t][r]*avd; }
    } else {
      if (l16 < hhi*C - t*16){
        #pragma unroll
        for (int r=0;r<4;r++){ ps[r][hlo] += acc[t][r]*avs; pd[r][hlo] += acc[t][r]*avd; }
      } else {
        #pragma unroll
        for (int r=0;r<4;r++){ ps[r][hhi] += acc[t][r]*avs; pd[r][hhi] += acc[t][r]*avd; }
      }
    }
  }
  #pragma unroll
  for (int off=1; off<16; off<<=1){
    #pragma unroll
    for (int r=0;r<4;r++)
      #pragma unroll
      for (int h=0;h<4;h++){
        ps[r][h] += __shfl_xor(ps[r][h], off);
        pd[r][h] += __shfl_xor(pd[r][h], off);
      }
  }
  float vs = 0.f, vd = 0.f;
  #pragma unroll
  for (int r=0;r<4;r++)
    #pragma unroll
    for (int h=0;h<4;h++)
      if (l16 == r*4 + h){ vs = ps[r][h]; vd = pd[r][h]; }
  int wrow = rowbase + quad*4 + (l16 >> 2);
  if (wrow < N){
    als[wrow*4 + (l16 & 3)] = vs;
    ald[wrow*4 + (l16 & 3)] = vd;
  }
}

// ---------------- layer-1 aggregation: wave per node (round-2 structure) ----------------
__global__ __launch_bounds__(256) void agg1(const u16* __restrict__ h1,
    const float* __restrict__ als, const float* __restrict__ ald, const void* __restrict__ b1,
    const int* __restrict__ rp, const int* __restrict__ psrc,
    u16* __restrict__ hrelu, int N, const int* __restrict__ flag){
  __shared__ __align__(16) int   sbuf[4][16];
  __shared__ __align__(16) float ebT[4][4*20];   // stride 20 dwords = 80 B (16-aligned)
  const bool isbf = *flag != 0;
  int wave = threadIdx.x >> 6, lane = threadIdx.x & 63;
  int node = blockIdx.x*4 + wave;
  bool live = node < N;
  int nd = live ? node : 0;
  int hd = lane >> 4;                 // head of output channels 2*lane
  int eidx = lane >> 2, hA = lane & 3;
  int beg = __builtin_amdgcn_readfirstlane(rp[nd]);
  int end = __builtin_amdgcn_readfirstlane(rp[nd+1]);
  if (!live){ beg = 0; end = 0; }
  float advA = ald[nd*4 + hA];
  const char* hb = (const char*)h1;
  int lane4 = lane << 2;
  int* sb = sbuf[wave];
  float* eb = ebT[wave];
  float a0 = 0.f, a1 = 0.f;
  float sp = 0.f;
  for (int cbeg = beg; cbeg < end; cbeg += 16){
    int cnt = min(16, end - cbeg);
    int e = cbeg + eidx;
    bool vv = e < end;
    int ec = vv ? e : beg;
    int s = psrc[ec];
    float lv = als[s*4 + hA] + advA;
    lv = fmaxf(lv, 0.2f*lv);
    float ex = vv ? __expf(lv) : 0.f;
    sp += ex;
    eb[hA*20 + eidx] = ex;
    if (hA == 0) sb[eidx] = vv ? (s << 8) : 0;   // row byte offset (256 B rows)
    for (int j0 = 0; j0 < cnt; j0 += 4){
      i32x4 off4 = *(const i32x4*)&sb[j0];                 // uniform b128 broadcast
      f32x4 ex4  = *(const f32x4*)&eb[hd*20 + j0];         // per-head-group b128
      u32 p[4];
      #pragma unroll
      for (int i=0;i<4;i++) p[i] = *(const u32*)(hb + (u32)(off4[i] + lane4));
      #pragma unroll
      for (int i=0;i<4;i++){
        union{u32 u; float f;} w;
        w.u = p[i] << 16;         a0 += ex4[i]*w.f;
        w.u = p[i] & 0xffff0000u; a1 += ex4[i]*w.f;
      }
    }
  }
  sp += __shfl_xor(sp, 4);  sp += __shfl_xor(sp, 8);
  sp += __shfl_xor(sp, 16); sp += __shfl_xor(sp, 32);
  float sum = __shfl(sp, hd);          // lane h holds head-h sum
  if (live){
    float inv = 1.f/(sum + 1e-16f);
    float v0 = a0*inv + loadv(b1, 2*lane,     isbf);
    float v1 = a1*inv + loadv(b1, 2*lane + 1, isbf);
    v0 = v0 > 0.f ? v0 : 0.f;
    v1 = v1 > 0.f ? v1 : 0.f;
    u32 packed = (u32)f2b(v0) | ((u32)f2b(v1) << 16);
    *(u32*)(hrelu + (size_t)node*128 + 2*lane) = packed;
  }
}

// ---------------- layer-2 aggregation + head-mean + bias + log_softmax ----------------
__global__ __launch_bounds__(256) void agg2(const u16* __restrict__ h2m, const u16* __restrict__ h2t,
    const float* __restrict__ als, const float* __restrict__ ald, const void* __restrict__ b2,
    const int* __restrict__ rp, const int* __restrict__ psrc,
    void* __restrict__ out, int N, const int* __restrict__ flag){
  __shared__ __align__(16) int   sbuf[4][16];
  __shared__ __align__(16) float ebT[4][4*20];
  __shared__ __align__(16) float sm[4][160];
  const bool isbf = *flag != 0;
  int wave = threadIdx.x >> 6, lane = threadIdx.x & 63;
  int node = blockIdx.x*4 + wave;
  bool live = node < N;
  int nd = live ? node : 0;
  int g = lane >> 4, s = lane & 15;
  int hm = s / 5;                       // head of main channels 8s..8s+7
  int moff = s << 4;                    // main byte offset within 256B row
  int tof  = s << 2;                    // tail byte offset within 64B row
  int eidx = lane >> 2, hA = lane & 3;
  int beg = __builtin_amdgcn_readfirstlane(rp[nd]);
  int end = __builtin_amdgcn_readfirstlane(rp[nd+1]);
  if (!live){ beg = 0; end = 0; }
  float advA = ald[nd*4 + hA];
  const char* hbm = (const char*)h2m;
  const char* hbt = (const char*)h2t;
  int* sb = sbuf[wave];
  float* eb = ebT[wave];
  float am[8] = {0.f,0.f,0.f,0.f,0.f,0.f,0.f,0.f};
  float at0 = 0.f, at1 = 0.f;
  float sp = 0.f;
  for (int cbeg = beg; cbeg < end; cbeg += 16){
    int cnt = min(16, end - cbeg);
    int e = cbeg + eidx;
    bool vv = e < end;
    int ec = vv ? e : beg;
    int src = psrc[ec];
    float lv = als[src*4 + hA] + advA;
    lv = fmaxf(lv, 0.2f*lv);
    float ex = vv ? __expf(lv) : 0.f;
    sp += ex;
    eb[hA*20 + eidx] = ex;
    if (hA == 0) sb[eidx] = vv ? src : 0;       // raw src index
    for (int j0 = 0; j0 < cnt; j0 += 4){
      int sv    = sb[j0 + g];                    // 4 srcs, 16-lane broadcast
      float exm = eb[hm*20 + j0 + g];
      float ext = eb[3*20  + j0 + g];
      i32x4 P = *(const i32x4*)(hbm + ((((u32)sv) << 8) + moff));
      u32   q = *(const u32*) (hbt + ((((u32)sv) << 6) + tof));
      union{u32 u; float f;} w;
      #pragma unroll
      for (int i=0;i<4;i++){
        u32 pv = (u32)P[i];
        w.u = pv << 16;         am[2*i]   += exm*w.f;
        w.u = pv & 0xffff0000u; am[2*i+1] += exm*w.f;
      }
      w.u = q << 16;         at0 += ext*w.f;
      w.u = q & 0xffff0000u; at1 += ext*w.f;
    }
  }
  // softmax denominators: lane l ends with sum of head (l&3)
  sp += __shfl_xor(sp, 4);  sp += __shfl_xor(sp, 8);
  sp += __shfl_xor(sp, 16); sp += __shfl_xor(sp, 32);
  float Sm = __shfl(sp, hm);
  float S3 = __shfl(sp, 3);
  // cross-group accumulator reduce (edges were partitioned across the 4 groups)
  #pragma unroll
  for (int k=0;k<8;k++){ am[k] += __shfl_xor(am[k],16); am[k] += __shfl_xor(am[k],32); }
  at0 += __shfl_xor(at0,16); at0 += __shfl_xor(at0,32);
  at1 += __shfl_xor(at1,16); at1 += __shfl_xor(at1,32);
  if (lane < 16){
    float invm = 1.f/(Sm + 1e-16f);
    float invt = 1.f/(S3 + 1e-16f);
    f32x4 v0 = {am[0]*invm, am[1]*invm, am[2]*invm, am[3]*invm};
    f32x4 v1 = {am[4]*invm, am[5]*invm, am[6]*invm, am[7]*invm};
    *(f32x4*)&sm[wave][8*s]     = v0;
    *(f32x4*)&sm[wave][8*s + 4] = v1;
    sm[wave][128 + 2*s] = at0*invt;
    sm[wave][129 + 2*s] = at1*invt;
  }
  __syncthreads();
  float v = -__builtin_inff();
  if (lane < 40)
    v = (sm[wave][lane] + sm[wave][40+lane] + sm[wave][80+lane] + sm[wave][120+lane]) * 0.25f
        + loadv(b2, lane, isbf);
  float mxo = v;
  for (int o = 32; o; o >>= 1) mxo = fmaxf(mxo, __shfl_xor(mxo, o));
  float exl = (lane < 40) ? __expf(v - mxo) : 0.f;
  float S = exl;
  for (int o = 32; o; o >>= 1) S += __shfl_xor(S, o);
  if (live && lane < 40){
    float r = v - mxo - __logf(S);
    if (isbf) ((u16*)out)[(size_t)node*40 + lane] = f2b(r);
    else      ((float*)out)[(size_t)node*40 + lane] = r;
  }
}

extern "C" void kernel_launch(void* const* d_in, const int* in_sizes, int n_in,
                              void* d_out, int out_size, void* d_ws, size_t ws_size,
                              hipStream_t stream){
  const void* x   = d_in[0];
  const int*  ei  = (const int*)d_in[1];
  const void* W1  = d_in[2];
  const void* as1 = d_in[3];
  const void* ad1 = d_in[4];
  const void* b1  = d_in[5];
  const void* W2  = d_in[6];
  const void* as2 = d_in[7];
  const void* ad2 = d_in[8];
  const void* b2  = d_in[9];

  const int N = in_sizes[0] / 128;
  const int E = in_sizes[1] / 2;
  const int* esrc = ei;
  const int* edst = ei + E;

  char* w = (char*)d_ws;
  size_t off = 0;
  auto take = [&](size_t bytes)->void*{
    void* p = w + off;
    off = (off + bytes + 255) & ~(size_t)255;
    return p;
  };
  u16*   h12    = (u16*)take((size_t)N*128*2);   // h1 [N,128] then h2m [N,128] (aliased)
  u16*   h2t    = (u16*)take((size_t)N*32*2);    // h2 tail channels 128..159
  u16*   hrelu  = (u16*)take((size_t)N*128*2);
  float* als1   = (float*)take((size_t)N*4*4);
  float* ald1   = (float*)take((size_t)N*4*4);
  float* als2   = (float*)take((size_t)N*4*4);
  float* ald2   = (float*)take((size_t)N*4*4);
  int*   rowptr = (int*)take((size_t)(N+1)*4);
  int*   counts = (int*)take((size_t)N*4);
  int*   bsum   = (int*)take(1024*4);
  int*   bscan  = (int*)take(1024*4);
  int*   psrc   = (int*)take((size_t)E*4);
  int*   flag   = (int*)take(64);
  u16*   wt1    = (u16*)take(128*128*2);
  u16*   wt2    = (u16*)take(160*128*2);

  const int B = (N + 255) / 256;
  const int NCHUNK = 128;               // blocks per region-group; scatter grid = 8*NCHUNK
  const int INIT_W = 128*128 + 128*160;

  detect_bf16<<<1, 256, 0, stream>>>(x, N*128, flag);
  init_k<<<(INIT_W + N + 255)/256, 256, 0, stream>>>(W1, W2, wt1, wt2, counts, N, flag);

  // CSR: single-pass count (cheap atomics, edge list read once) + scan;
  // scan_final re-zeroes counts for the XCD-partitioned scatter pass
  count_1p<<<2048, 256, 0, stream>>>(edst, counts, E);
  scan_bsum<<<B, 256, 0, stream>>>(counts, bsum, N);
  scan_top<<<1, 1024, 0, stream>>>(bsum, bscan, B);
  scan_final<<<B, 256, 0, stream>>>(counts, counts, bscan, rowptr, N, E);
  scatter_x<<<8*NCHUNK, 256, 0, stream>>>(esrc, edst, rowptr, counts, psrc, E, N, NCHUNK);

  // layer 1 (gemm + fused al epilogue)
  gemm_al<128,32><<<(N+63)/64, 256, 0, stream>>>(x, wt1, as1, ad1, h12, h2t /*unused*/,
                                                 als1, ald1, N, flag, flag);
  agg1<<<(N+3)/4, 256, 0, stream>>>(h12, als1, ald1, b1, rowptr, psrc, hrelu, N, flag);

  // layer 2 (h2m overwrites h1 region; hrelu input is internal bf16 -> flag+1)
  gemm_al<160,40><<<(N+63)/64, 256, 0, stream>>>(hrelu, wt2, as2, ad2, h12, h2t,
                                                 als2, ald2, N, flag+1, flag);
  agg2<<<(N+3)/4, 256, 0, stream>>>(h12, h2t, als2, ald2, b2, rowptr, psrc, d_out, N, flag);
}

// Round 10
// 474.866 us; speedup vs baseline: 1.0737x; 1.0032x over previous
//
#include <hip/hip_runtime.h>

typedef short short8 __attribute__((ext_vector_type(8)));
typedef float f32x4 __attribute__((ext_vector_type(4)));
typedef int   i32x4 __attribute__((ext_vector_type(4)));
typedef unsigned short u16;
typedef unsigned int u32;

__device__ __forceinline__ float b2f(u16 u){ union{u32 i; float f;} v; v.i=((u32)u)<<16; return v.f; }
__device__ __forceinline__ u16 f2b(float f){ union{float f; u32 i;} v; v.f=f; return (u16)((v.i + 0x7fffu + ((v.i>>16)&1u))>>16); }
__device__ __forceinline__ float loadv(const void* p, long i, bool isbf){
  return isbf ? b2f(((const u16*)p)[i]) : ((const float*)p)[i];
}

// ---------------- dtype detector: bf16 buffers vs fp32 buffers ----------------
__global__ void detect_bf16(const void* x, int n, int* flag){
  __shared__ int cnt;
  if (threadIdx.x==0) cnt = 0;
  __syncthreads();
  int m = n < 4096 ? n : 4096;
  int good = 0;
  for (int i = threadIdx.x; i < m; i += 256){
    u16 u = ((const u16*)x)[i];
    int e = (u >> 7) & 0xff;
    if (u == 0 || (e >= 100 && e <= 140)) good++;
  }
  atomicAdd(&cnt, good);
  __syncthreads();
  if (threadIdx.x==0){
    flag[0] = (cnt >= (m*3)/4) ? 1 : 0;
    flag[1] = 1;  // constant "is bf16" for internal buffers
  }
}

// ---------------- fused init ----------------
// A: WT1[c][k] (128x128)  B: WT2[c][k] (160 cols x 128)  C: WS1 hi/lo  D: WS2 hi/lo
// E: counts = 0.  WS[k][h] = sum_c W[k][h*C+c]*a[h][c] -> al = X @ WS (associativity),
// stored as bf16 hi (cols 0-7: als h, ald h) + bf16 lo (cols 8-15) for precision.
__global__ __launch_bounds__(256) void init_k(const void* __restrict__ W1, const void* __restrict__ W2,
                                              const void* __restrict__ as1, const void* __restrict__ ad1,
                                              const void* __restrict__ as2, const void* __restrict__ ad2,
                                              u16* __restrict__ WT1, u16* __restrict__ WT2,
                                              u16* __restrict__ WS1, u16* __restrict__ WS2,
                                              int* __restrict__ counts, int N, const int* __restrict__ flag){
  const bool wbf = *flag != 0;
  int gid = blockIdx.x*256 + threadIdx.x;
  if (gid < 16384){
    int i = gid, k = i >> 7, c = i & 127;
    WT1[c*128 + k] = wbf ? ((const u16*)W1)[i] : f2b(((const float*)W1)[i]);
  } else if (gid < 36864){
    int i = gid - 16384, k = i / 160, c = i - k*160;
    WT2[c*128 + k] = wbf ? ((const u16*)W2)[i] : f2b(((const float*)W2)[i]);
  } else if (gid < 37888){
    int i = gid - 36864, col = i >> 7, k = i & 127;   // col 0..7
    int h = col & 3;
    const void* av = (col < 4) ? as1 : ad1;
    float s = 0.f;
    for (int c = 0; c < 32; c++)
      s += loadv(W1, (long)k*128 + h*32 + c, wbf) * loadv(av, h*32 + c, wbf);
    u16 hi = f2b(s);
    WS1[col*128 + k] = hi;
    WS1[(col+8)*128 + k] = f2b(s - b2f(hi));
  } else if (gid < 38912){
    int i = gid - 37888, col = i >> 7, k = i & 127;
    int h = col & 3;
    const void* av = (col < 4) ? as2 : ad2;
    float s = 0.f;
    for (int c = 0; c < 40; c++)
      s += loadv(W2, (long)k*160 + h*40 + c, wbf) * loadv(av, h*40 + c, wbf);
    u16 hi = f2b(s);
    WS2[col*128 + k] = hi;
    WS2[(col+8)*128 + k] = f2b(s - b2f(hi));
  } else {
    int i = gid - 38912;
    if (i < N) counts[i] = 0;
  }
}

// ---------------- CSR count: single-pass (edge list read once; atomics are small
// L2-side RMW messages, no write-allocate amplification - round-5/9 evidence) ----
__global__ __launch_bounds__(256) void count_1p(const int* __restrict__ dst, int* __restrict__ counts, int E){
  int i = blockIdx.x*256 + threadIdx.x;
  int stride = gridDim.x*256;
  for (int e = i; e < E; e += stride) atomicAdd(&counts[dst[e]], 1);
}

// ---------------- CSR scatter: XCD-partitioned (psrc lines fill completely in the
// owning XCD's L2 before write-back; single-pass variant had 16x amplification) ----
__global__ __launch_bounds__(256) void scatter_x(const int* __restrict__ src, const int* __restrict__ dst,
    const int* __restrict__ rp, int* __restrict__ cur,
    int* __restrict__ psrc, int E, int N, int nchunk){
  int r = blockIdx.x & 7;
  int chunk = blockIdx.x >> 3;
  int lo = (int)(((long)N * r) >> 3);
  int hi = (int)(((long)N * (r+1)) >> 3);
  int per = (E + nchunk - 1) / nchunk;
  int s = chunk * per, t = min(E, s + per);
  for (int e = s + threadIdx.x; e < t; e += 256){
    int d = dst[e];
    if (d >= lo && d < hi){
      int pos = rp[d] + atomicAdd(&cur[d], 1);
      psrc[pos] = src[e];
    }
  }
}

__global__ __launch_bounds__(256) void scan_bsum(const int* __restrict__ counts, int* __restrict__ bsum, int N){
  __shared__ int sm[256];
  int t = threadIdx.x, i = blockIdx.x*256 + t;
  sm[t] = (i < N) ? counts[i] : 0;
  __syncthreads();
  for (int off = 128; off; off >>= 1){
    if (t < off) sm[t] += sm[t+off];
    __syncthreads();
  }
  if (t == 0) bsum[blockIdx.x] = sm[0];
}

__global__ __launch_bounds__(1024) void scan_top(const int* __restrict__ bsum, int* __restrict__ bscan, int B){
  __shared__ int sm[1024];
  int t = threadIdx.x;
  int v = (t < B) ? bsum[t] : 0;
  sm[t] = v;
  __syncthreads();
  for (int off = 1; off < 1024; off <<= 1){
    int x = (t >= off) ? sm[t-off] : 0;
    __syncthreads();
    sm[t] += x;
    __syncthreads();
  }
  if (t < B) bscan[t] = sm[t] - v;   // exclusive
}

// scan_final also zeroes counts (value already consumed) -> no 2nd memset
__global__ __launch_bounds__(256) void scan_final(const int* __restrict__ counts_in, int* __restrict__ counts_clr,
                                                  const int* __restrict__ bscan,
                                                  int* __restrict__ rp, int N, int E){
  __shared__ int sm[256];
  int t = threadIdx.x, i = blockIdx.x*256 + t;
  int v = (i < N) ? counts_in[i] : 0;
  sm[t] = v;
  __syncthreads();
  for (int off = 1; off < 256; off <<= 1){
    int x = (t >= off) ? sm[t-off] : 0;
    __syncthreads();
    sm[t] += x;
    __syncthreads();
  }
  if (i < N){ rp[i] = bscan[blockIdx.x] + sm[t] - v; counts_clr[i] = 0; }
  if (i == 0) rp[N] = E;
}

// ---------------- GEMM + MFMA-fused attention pre-logits ----------------
// OUT[N,M] = X[N,128] * W[128,M] (bf16 out, fp32 acc). Cols 0..127 -> OUT,
// cols 128.. -> OUT2 (line-aligned split for the agg gather). al epilogue:
// one extra MFMA tile against WS (= W@a, hi/lo bf16 split) -> acc[NT] holds
// als (cols 0-3) / ald (cols 4-7) in fp32; lo parts in cols 8-15 are folded
// in with one shfl_xor(8). Replaces the 256-op shfl butterfly of round 7-9.
template<int M>
__global__ __launch_bounds__(256) void gemm_al(const void* __restrict__ X, const u16* __restrict__ WT,
                                               const u16* __restrict__ WS,
                                               u16* __restrict__ OUT, u16* __restrict__ OUT2,
                                               float* __restrict__ als, float* __restrict__ ald,
                                               int N, const int* __restrict__ flagX){
  __shared__ u16 wt[M+16][136];         // +8 pad: 2-way bank alias only (free)
  const bool xbf = *flagX != 0;
  int tid = threadIdx.x;
  for (int i = tid; i < M*16; i += 256){
    int c = i >> 4, k8 = (i & 15) << 3;
    *(short8*)&wt[c][k8] = *(const short8*)&WT[c*128 + k8];
  }
  for (int i = tid; i < 256; i += 256){
    int c = i >> 4, k8 = (i & 15) << 3;
    *(short8*)&wt[M + c][k8] = *(const short8*)&WS[c*128 + k8];
  }
  __syncthreads();
  int wave = tid >> 6, lane = tid & 63;
  int quad = lane >> 4, l16 = lane & 15;
  int rowbase = blockIdx.x*64 + wave*16;
  int rr = rowbase + l16; if (rr >= N) rr = N-1;
  const int NT = M/16;
  f32x4 acc[NT+1];
  #pragma unroll
  for (int t=0;t<NT+1;t++) acc[t] = (f32x4){0.f,0.f,0.f,0.f};
  #pragma unroll
  for (int kt = 0; kt < 4; kt++){
    int kb = kt*32 + quad*8;
    short8 a;
    if (xbf){
      a = *(const short8*)((const u16*)X + (size_t)rr*128 + kb);
    } else {
      const float* xf = (const float*)X + (size_t)rr*128 + kb;
      #pragma unroll
      for (int j=0;j<8;j++) a[j] = (short)f2b(xf[j]);
    }
    #pragma unroll
    for (int t=0;t<NT+1;t++){
      short8 b = *(const short8*)&wt[t*16 + l16][kb];
      acc[t] = __builtin_amdgcn_mfma_f32_16x16x32_bf16(a, b, acc[t], 0, 0, 0);
    }
  }
  // ---- store OUT (bf16) ----
  #pragma unroll
  for (int t=0;t<NT;t++){
    #pragma unroll
    for (int r=0;r<4;r++){
      int row = rowbase + quad*4 + r;
      if (row < N){
        u16 val = f2b(acc[t][r]);
        if (M > 128 && t*16 >= 128) OUT2[(size_t)row*32 + (t*16 - 128) + l16] = val;
        else                        OUT [(size_t)row*128 + t*16 + l16]        = val;
      }
    }
  }
  // ---- al epilogue: fold lo columns, write 8 lanes x 4 rows ----
  #pragma unroll
  for (int r=0;r<4;r++){
    float hi = acc[NT][r];
    float v = hi + __shfl_xor(hi, 8);
    int row = rowbase + quad*4 + r;
    if (row < N && l16 < 8){
      if (l16 < 4) als[row*4 + l16] = v;
      else         ald[row*4 + l16 - 4] = v;
    }
  }
}

// ---------------- layer-1 aggregation: wave per node (round-2 structure) ----------------
__global__ __launch_bounds__(256) void agg1(const u16* __restrict__ h1,
    const float* __restrict__ als, const float* __restrict__ ald, const void* __restrict__ b1,
    const int* __restrict__ rp, const int* __restrict__ psrc,
    u16* __restrict__ hrelu, int N, const int* __restrict__ flag){
  __shared__ __align__(16) int   sbuf[4][16];
  __shared__ __align__(16) float ebT[4][4*20];   // stride 20 dwords = 80 B (16-aligned)
  const bool isbf = *flag != 0;
  int wave = threadIdx.x >> 6, lane = threadIdx.x & 63;
  int node = blockIdx.x*4 + wave;
  bool live = node < N;
  int nd = live ? node : 0;
  int hd = lane >> 4;                 // head of output channels 2*lane
  int eidx = lane >> 2, hA = lane & 3;
  int beg = __builtin_amdgcn_readfirstlane(rp[nd]);
  int end = __builtin_amdgcn_readfirstlane(rp[nd+1]);
  if (!live){ beg = 0; end = 0; }
  float advA = ald[nd*4 + hA];
  const char* hb = (const char*)h1;
  int lane4 = lane << 2;
  int* sb = sbuf[wave];
  float* eb = ebT[wave];
  float a0 = 0.f, a1 = 0.f;
  float sp = 0.f;
  for (int cbeg = beg; cbeg < end; cbeg += 16){
    int cnt = min(16, end - cbeg);
    int e = cbeg + eidx;
    bool vv = e < end;
    int ec = vv ? e : beg;
    int s = psrc[ec];
    float lv = als[s*4 + hA] + advA;
    lv = fmaxf(lv, 0.2f*lv);
    float ex = vv ? __expf(lv) : 0.f;
    sp += ex;
    eb[hA*20 + eidx] = ex;
    if (hA == 0) sb[eidx] = vv ? (s << 8) : 0;   // row byte offset (256 B rows)
    for (int j0 = 0; j0 < cnt; j0 += 4){
      i32x4 off4 = *(const i32x4*)&sb[j0];                 // uniform b128 broadcast
      f32x4 ex4  = *(const f32x4*)&eb[hd*20 + j0];         // per-head-group b128
      u32 p[4];
      #pragma unroll
      for (int i=0;i<4;i++) p[i] = *(const u32*)(hb + (u32)(off4[i] + lane4));
      #pragma unroll
      for (int i=0;i<4;i++){
        union{u32 u; float f;} w;
        w.u = p[i] << 16;         a0 += ex4[i]*w.f;
        w.u = p[i] & 0xffff0000u; a1 += ex4[i]*w.f;
      }
    }
  }
  sp += __shfl_xor(sp, 4);  sp += __shfl_xor(sp, 8);
  sp += __shfl_xor(sp, 16); sp += __shfl_xor(sp, 32);
  float sum = __shfl(sp, hd);          // lane h holds head-h sum
  if (live){
    float inv = 1.f/(sum + 1e-16f);
    float v0 = a0*inv + loadv(b1, 2*lane,     isbf);
    float v1 = a1*inv + loadv(b1, 2*lane + 1, isbf);
    v0 = v0 > 0.f ? v0 : 0.f;
    v1 = v1 > 0.f ? v1 : 0.f;
    u32 packed = (u32)f2b(v0) | ((u32)f2b(v1) << 16);
    *(u32*)(hrelu + (size_t)node*128 + 2*lane) = packed;
  }
}

// ---------------- layer-2 aggregation + head-mean + bias + log_softmax ----------------
__global__ __launch_bounds__(256) void agg2(const u16* __restrict__ h2m, const u16* __restrict__ h2t,
    const float* __restrict__ als, const float* __restrict__ ald, const void* __restrict__ b2,
    const int* __restrict__ rp, const int* __restrict__ psrc,
    void* __restrict__ out, int N, const int* __restrict__ flag){
  __shared__ __align__(16) int   sbuf[4][16];
  __shared__ __align__(16) float ebT[4][4*20];
  __shared__ __align__(16) float sm[4][160];
  const bool isbf = *flag != 0;
  int wave = threadIdx.x >> 6, lane = threadIdx.x & 63;
  int node = blockIdx.x*4 + wave;
  bool live = node < N;
  int nd = live ? node : 0;
  int g = lane >> 4, s = lane & 15;
  int hm = s / 5;                       // head of main channels 8s..8s+7
  int moff = s << 4;                    // main byte offset within 256B row
  int tof  = s << 2;                    // tail byte offset within 64B row
  int eidx = lane >> 2, hA = lane & 3;
  int beg = __builtin_amdgcn_readfirstlane(rp[nd]);
  int end = __builtin_amdgcn_readfirstlane(rp[nd+1]);
  if (!live){ beg = 0; end = 0; }
  float advA = ald[nd*4 + hA];
  const char* hbm = (const char*)h2m;
  const char* hbt = (const char*)h2t;
  int* sb = sbuf[wave];
  float* eb = ebT[wave];
  float am[8] = {0.f,0.f,0.f,0.f,0.f,0.f,0.f,0.f};
  float at0 = 0.f, at1 = 0.f;
  float sp = 0.f;
  for (int cbeg = beg; cbeg < end; cbeg += 16){
    int cnt = min(16, end - cbeg);
    int e = cbeg + eidx;
    bool vv = e < end;
    int ec = vv ? e : beg;
    int src = psrc[ec];
    float lv = als[src*4 + hA] + advA;
    lv = fmaxf(lv, 0.2f*lv);
    float ex = vv ? __expf(lv) : 0.f;
    sp += ex;
    eb[hA*20 + eidx] = ex;
    if (hA == 0) sb[eidx] = vv ? src : 0;       // raw src index
    for (int j0 = 0; j0 < cnt; j0 += 4){
      int sv    = sb[j0 + g];                    // 4 srcs, 16-lane broadcast
      float exm = eb[hm*20 + j0 + g];
      float ext = eb[3*20  + j0 + g];
      i32x4 P = *(const i32x4*)(hbm + ((((u32)sv) << 8) + moff));
      u32   q = *(const u32*) (hbt + ((((u32)sv) << 6) + tof));
      union{u32 u; float f;} w;
      #pragma unroll
      for (int i=0;i<4;i++){
        u32 pv = (u32)P[i];
        w.u = pv << 16;         am[2*i]   += exm*w.f;
        w.u = pv & 0xffff0000u; am[2*i+1] += exm*w.f;
      }
      w.u = q << 16;         at0 += ext*w.f;
      w.u = q & 0xffff0000u; at1 += ext*w.f;
    }
  }
  // softmax denominators: lane l ends with sum of head (l&3)
  sp += __shfl_xor(sp, 4);  sp += __shfl_xor(sp, 8);
  sp += __shfl_xor(sp, 16); sp += __shfl_xor(sp, 32);
  float Sm = __shfl(sp, hm);
  float S3 = __shfl(sp, 3);
  // cross-group accumulator reduce (edges were partitioned across the 4 groups)
  #pragma unroll
  for (int k=0;k<8;k++){ am[k] += __shfl_xor(am[k],16); am[k] += __shfl_xor(am[k],32); }
  at0 += __shfl_xor(at0,16); at0 += __shfl_xor(at0,32);
  at1 += __shfl_xor(at1,16); at1 += __shfl_xor(at1,32);
  if (lane < 16){
    float invm = 1.f/(Sm + 1e-16f);
    float invt = 1.f/(S3 + 1e-16f);
    f32x4 v0 = {am[0]*invm, am[1]*invm, am[2]*invm, am[3]*invm};
    f32x4 v1 = {am[4]*invm, am[5]*invm, am[6]*invm, am[7]*invm};
    *(f32x4*)&sm[wave][8*s]     = v0;
    *(f32x4*)&sm[wave][8*s + 4] = v1;
    sm[wave][128 + 2*s] = at0*invt;
    sm[wave][129 + 2*s] = at1*invt;
  }
  __syncthreads();
  float v = -__builtin_inff();
  if (lane < 40)
    v = (sm[wave][lane] + sm[wave][40+lane] + sm[wave][80+lane] + sm[wave][120+lane]) * 0.25f
        + loadv(b2, lane, isbf);
  float mxo = v;
  for (int o = 32; o; o >>= 1) mxo = fmaxf(mxo, __shfl_xor(mxo, o));
  float exl = (lane < 40) ? __expf(v - mxo) : 0.f;
  float S = exl;
  for (int o = 32; o; o >>= 1) S += __shfl_xor(S, o);
  if (live && lane < 40){
    float r = v - mxo - __logf(S);
    if (isbf) ((u16*)out)[(size_t)node*40 + lane] = f2b(r);
    else      ((float*)out)[(size_t)node*40 + lane] = r;
  }
}

extern "C" void kernel_launch(void* const* d_in, const int* in_sizes, int n_in,
                              void* d_out, int out_size, void* d_ws, size_t ws_size,
                              hipStream_t stream){
  const void* x   = d_in[0];
  const int*  ei  = (const int*)d_in[1];
  const void* W1  = d_in[2];
  const void* as1 = d_in[3];
  const void* ad1 = d_in[4];
  const void* b1  = d_in[5];
  const void* W2  = d_in[6];
  const void* as2 = d_in[7];
  const void* ad2 = d_in[8];
  const void* b2  = d_in[9];

  const int N = in_sizes[0] / 128;
  const int E = in_sizes[1] / 2;
  const int* esrc = ei;
  const int* edst = ei + E;

  char* w = (char*)d_ws;
  size_t off = 0;
  auto take = [&](size_t bytes)->void*{
    void* p = w + off;
    off = (off + bytes + 255) & ~(size_t)255;
    return p;
  };
  u16*   h12    = (u16*)take((size_t)N*128*2);   // h1 [N,128] then h2m [N,128] (aliased)
  u16*   h2t    = (u16*)take((size_t)N*32*2);    // h2 tail channels 128..159
  u16*   hrelu  = (u16*)take((size_t)N*128*2);
  float* als1   = (float*)take((size_t)N*4*4);
  float* ald1   = (float*)take((size_t)N*4*4);
  float* als2   = (float*)take((size_t)N*4*4);
  float* ald2   = (float*)take((size_t)N*4*4);
  int*   rowptr = (int*)take((size_t)(N+1)*4);
  int*   counts = (int*)take((size_t)N*4);
  int*   bsum   = (int*)take(1024*4);
  int*   bscan  = (int*)take(1024*4);
  int*   psrc   = (int*)take((size_t)E*4);
  int*   flag   = (int*)take(64);
  u16*   wt1    = (u16*)take(128*128*2);
  u16*   wt2    = (u16*)take(160*128*2);
  u16*   ws1    = (u16*)take(16*128*2);
  u16*   ws2    = (u16*)take(16*128*2);

  const int B = (N + 255) / 256;
  const int NCHUNK = 128;               // blocks per region-group; scatter grid = 8*NCHUNK
  const int INIT_W = 16384 + 20480 + 1024 + 1024;

  detect_bf16<<<1, 256, 0, stream>>>(x, N*128, flag);
  init_k<<<(INIT_W + N + 255)/256, 256, 0, stream>>>(W1, W2, as1, ad1, as2, ad2,
                                                     wt1, wt2, ws1, ws2, counts, N, flag);

  // CSR: single-pass count + scan; scan_final re-zeroes counts for scatter
  count_1p<<<2048, 256, 0, stream>>>(edst, counts, E);
  scan_bsum<<<B, 256, 0, stream>>>(counts, bsum, N);
  scan_top<<<1, 1024, 0, stream>>>(bsum, bscan, B);
  scan_final<<<B, 256, 0, stream>>>(counts, counts, bscan, rowptr, N, E);
  scatter_x<<<8*NCHUNK, 256, 0, stream>>>(esrc, edst, rowptr, counts, psrc, E, N, NCHUNK);

  // layer 1 (gemm + MFMA-fused al epilogue)
  gemm_al<128><<<(N+63)/64, 256, 0, stream>>>(x, wt1, ws1, h12, h2t /*unused*/,
                                              als1, ald1, N, flag);
  agg1<<<(N+3)/4, 256, 0, stream>>>(h12, als1, ald1, b1, rowptr, psrc, hrelu, N, flag);

  // layer 2 (h2m overwrites h1 region; hrelu input is internal bf16 -> flag+1)
  gemm_al<160><<<(N+63)/64, 256, 0, stream>>>(hrelu, wt2, ws2, h12, h2t,
                                              als2, ald2, N, flag+1);
  agg2<<<(N+3)/4, 256, 0, stream>>>(h12, h2t, als2, ald2, b2, rowptr, psrc, d_out, N, flag);
}